// Round 1
// baseline (254.435 us; speedup 1.0000x reference)
//
#include <hip/hip_runtime.h>
#include <stdint.h>

#define C_DIM 128
#define N_DIM 131072
#define BN 64          // output rows per block
#define MROWS 73       // stored rows of d1/b2b (need rows [n0-8, n0+65) = 73 rows)
#define XROWS 82       // x rows [n0-9, n0+73)
#define LD 136         // LDS row stride in ushort: 128 + 8 pad (16B-aligned, 2-way-bank-free)

typedef __attribute__((ext_vector_type(8))) short short8;
typedef __attribute__((ext_vector_type(4))) float f32x4;

__device__ __forceinline__ ushort f2bf(float f) {
  union { float f; uint32_t u; } v; v.f = f;
  uint32_t r = v.u + 0x7FFFu + ((v.u >> 16) & 1u);   // RNE
  return (ushort)(r >> 16);
}
__device__ __forceinline__ float bf2f(uint32_t lo16) {
  union { uint32_t u; float f; } v; v.u = lo16 << 16;
  return v.f;
}
__device__ __forceinline__ uint32_t rotl32(uint32_t x, int r) { return (x << r) | (x >> (32 - r)); }

// Threefry-2x32, 20 rounds, key = (0, 42)  [jax.random.key(42)]
__device__ __forceinline__ void threefry42(uint32_t x0, uint32_t x1, uint32_t& o0, uint32_t& o1) {
  const uint32_t k0 = 0u, k1 = 42u, k2 = 0x1BD11BDAu ^ 0u ^ 42u;
  x0 += k0; x1 += k1;
#define TF_R(r) { x0 += x1; x1 = rotl32(x1, (r)); x1 ^= x0; }
  TF_R(13) TF_R(15) TF_R(26) TF_R(6)   x0 += k1; x1 += k2 + 1u;
  TF_R(17) TF_R(29) TF_R(16) TF_R(24)  x0 += k2; x1 += k0 + 2u;
  TF_R(13) TF_R(15) TF_R(26) TF_R(6)   x0 += k0; x1 += k1 + 3u;
  TF_R(17) TF_R(29) TF_R(16) TF_R(24)  x0 += k1; x1 += k2 + 4u;
  TF_R(13) TF_R(15) TF_R(26) TF_R(6)   x0 += k2; x1 += k0 + 5u;
#undef TF_R
  o0 = x0; o1 = x1;
}

// load 8 consecutive fp32 and convert to a bf16 A/B fragment
__device__ __forceinline__ short8 ldwfrag(const float* p) {
  float4 a = reinterpret_cast<const float4*>(p)[0];
  float4 b = reinterpret_cast<const float4*>(p)[1];
  short8 r;
  r[0] = (short)f2bf(a.x); r[1] = (short)f2bf(a.y); r[2] = (short)f2bf(a.z); r[3] = (short)f2bf(a.w);
  r[4] = (short)f2bf(b.x); r[5] = (short)f2bf(b.y); r[6] = (short)f2bf(b.z); r[7] = (short)f2bf(b.w);
  return r;
}

__device__ __forceinline__ f32x4 mfma16(short8 a, short8 b, f32x4 c) {
  return __builtin_amdgcn_mfma_f32_16x16x32_bf16(a, b, c, 0, 0, 0);
}

__global__ __launch_bounds__(256, 2) void fused_block(
    const float* __restrict__ x,
    const float* __restrict__ w_b1_dw,
    const float* __restrict__ w_b1_pw,
    const float* __restrict__ w_b2_1x1,
    const float* __restrict__ w_b2_dw,
    const float* __restrict__ w_b2_pw,
    const float* __restrict__ w_fusion,
    float* __restrict__ out)
{
  __shared__ ushort xs[XROWS * LD];     // x tile, bf16. row r <-> global n0-9+r
  __shared__ ushort bufA[MROWS * LD];   // d1, later d2. row r <-> global n0-8+r (d2: n0+r)
  __shared__ ushort bufB[MROWS * LD];   // b2b (masked), later b2. row r <-> n0-8+r (b2: n0+r)

  const int tid  = threadIdx.x;
  const int n0   = blockIdx.x * BN;
  const int lane = tid & 63;
  const int wv   = tid >> 6;
  const int q    = lane >> 4;     // quad
  const int lr   = lane & 15;
  const int ow   = wv * 32;       // this wave's O-slice base

  // ---- stage 1: global x -> xs (bf16), rows [n0-9, n0+73), zero-padded OOB
  for (int i = tid; i < XROWS * 32; i += 256) {
    int r = i >> 5, c4 = (i & 31) << 2;
    int g = n0 - 9 + r;
    float4 v = make_float4(0.f, 0.f, 0.f, 0.f);
    if (g >= 0 && g < N_DIM) v = reinterpret_cast<const float4*>(x)[g * 32 + (i & 31)];
    ushort4 s;
    s.x = f2bf(v.x); s.y = f2bf(v.y); s.z = f2bf(v.z); s.w = f2bf(v.w);
    *reinterpret_cast<ushort4*>(&xs[r * LD + c4]) = s;
  }
  __syncthreads();

  // ---- stage 2: dw1 (3-tap along N, only middle kernel column survives W=1 padding)
  {
    int c2 = (tid & 63) * 2;
    int rb = tid >> 6;
    float t0a = w_b1_dw[c2 * 9 + 1], t1a = w_b1_dw[c2 * 9 + 4], t2a = w_b1_dw[c2 * 9 + 7];
    float t0b = w_b1_dw[(c2 + 1) * 9 + 1], t1b = w_b1_dw[(c2 + 1) * 9 + 4], t2b = w_b1_dw[(c2 + 1) * 9 + 7];
    for (int k = 0; k < 20; ++k) {
      int r = rb + k * 4;                 // d1 row (global n0-8+r)
      if (r < MROWS) {
        uint32_t u0 = *reinterpret_cast<const uint32_t*>(&xs[r * LD + c2]);
        uint32_t u1 = *reinterpret_cast<const uint32_t*>(&xs[(r + 1) * LD + c2]);
        uint32_t u2 = *reinterpret_cast<const uint32_t*>(&xs[(r + 2) * LD + c2]);
        float lo = fmaxf(t0a * bf2f(u0 & 0xFFFFu) + t1a * bf2f(u1 & 0xFFFFu) + t2a * bf2f(u2 & 0xFFFFu), 0.f);
        float hi = fmaxf(t0b * bf2f(u0 >> 16) + t1b * bf2f(u1 >> 16) + t2b * bf2f(u2 >> 16), 0.f);
        uint32_t w = (uint32_t)f2bf(lo) | ((uint32_t)f2bf(hi) << 16);
        *reinterpret_cast<uint32_t*>(&bufA[r * LD + c2]) = w;
      }
    }
  }
  __syncthreads();

  // ---- stage 3: b2b = relu(d1 @ W1pw^T) + relu(x @ W2a^T)   (O-split: wave owns 32 channels)
  {
    short8 w1f[4][2], w2f[4][2];
    for (int kc = 0; kc < 4; ++kc)
      for (int ot = 0; ot < 2; ++ot) {
        int o = ow + ot * 16 + lr;
        int kk = kc * 32 + q * 8;
        w1f[kc][ot] = ldwfrag(w_b1_pw + o * 128 + kk);
        w2f[kc][ot] = ldwfrag(w_b2_1x1 + o * 128 + kk);
      }
    f32x4 zero = {0.f, 0.f, 0.f, 0.f};
    for (int mt = 0; mt < 5; ++mt) {      // 5 M-tiles cover rows 0..79 (rows>=73 discarded)
      f32x4 a1[2] = {zero, zero};
      f32x4 a2[2] = {zero, zero};
      int am = mt * 16 + lr;
      for (int kc = 0; kc < 4; ++kc) {
        int kk = kc * 32 + q * 8;
        short8 af1 = *reinterpret_cast<const short8*>(&bufA[am * LD + kk]);       // d1 row am
        short8 af2 = *reinterpret_cast<const short8*>(&xs[(am + 1) * LD + kk]);   // x at same global row
        for (int ot = 0; ot < 2; ++ot) {
          a1[ot] = mfma16(af1, w1f[kc][ot], a1[ot]);
          a2[ot] = mfma16(af2, w2f[kc][ot], a2[ot]);
        }
      }
      for (int ot = 0; ot < 2; ++ot)
        for (int j = 0; j < 4; ++j) {
          int row = mt * 16 + q * 4 + j;  // D layout: col=lane&15, row=quad*4+reg
          if (row < MROWS) {
            float v = fmaxf(a1[ot][j], 0.f) + fmaxf(a2[ot][j], 0.f);
            bufB[row * LD + ow + ot * 16 + lr] = f2bf(v);
          }
        }
    }
  }
  __syncthreads();

  // ---- stage 3b: Bernoulli mask (partitionable threefry: bits = y0^y1 of TF(0, i), i = c*N+n)
  // keep iff u < 0.5 iff MSB(bits)==0. Also zero rows whose global index is OOB (dw2 padding).
  for (int i = tid; i < MROWS * 128; i += 256) {
    int r = i >> 7, o = i & 127;
    int g = n0 - 8 + r;
    if (g < 0 || g >= N_DIM) {
      bufB[r * LD + o] = 0;
    } else {
      uint32_t idx = (uint32_t)o * (uint32_t)N_DIM + (uint32_t)g;
      uint32_t y0, y1;
      threefry42(0u, idx, y0, y1);
      if ((y0 ^ y1) & 0x80000000u) bufB[r * LD + o] = 0;
    }
  }
  __syncthreads();

  // ---- stage 4: dw2 on masked b2b -> d2 (bufA), rows j=0..63 use b2b rows j+7..j+9
  {
    int c2 = (tid & 63) * 2;
    int rb = tid >> 6;
    float t0a = w_b2_dw[c2 * 9 + 1], t1a = w_b2_dw[c2 * 9 + 4], t2a = w_b2_dw[c2 * 9 + 7];
    float t0b = w_b2_dw[(c2 + 1) * 9 + 1], t1b = w_b2_dw[(c2 + 1) * 9 + 4], t2b = w_b2_dw[(c2 + 1) * 9 + 7];
    for (int k = 0; k < 16; ++k) {
      int j = rb + k * 4;                 // output row (global n0+j)
      uint32_t u0 = *reinterpret_cast<const uint32_t*>(&bufB[(j + 7) * LD + c2]);
      uint32_t u1 = *reinterpret_cast<const uint32_t*>(&bufB[(j + 8) * LD + c2]);
      uint32_t u2 = *reinterpret_cast<const uint32_t*>(&bufB[(j + 9) * LD + c2]);
      float lo = fmaxf(t0a * bf2f(u0 & 0xFFFFu) + t1a * bf2f(u1 & 0xFFFFu) + t2a * bf2f(u2 & 0xFFFFu), 0.f);
      float hi = fmaxf(t0b * bf2f(u0 >> 16) + t1b * bf2f(u1 >> 16) + t2b * bf2f(u2 >> 16), 0.f);
      uint32_t w = (uint32_t)f2bf(lo) | ((uint32_t)f2bf(hi) << 16);
      *reinterpret_cast<uint32_t*>(&bufA[j * LD + c2]) = w;
    }
  }
  __syncthreads();

  // ---- stage 5: b2 = relu(d2 @ W2pw^T) -> bufB (A-layout staging for fusion)
  {
    short8 w3f[4][2];
    for (int kc = 0; kc < 4; ++kc)
      for (int ot = 0; ot < 2; ++ot) {
        int o = ow + ot * 16 + lr;
        int kk = kc * 32 + q * 8;
        w3f[kc][ot] = ldwfrag(w_b2_pw + o * 128 + kk);
      }
    f32x4 zero = {0.f, 0.f, 0.f, 0.f};
    for (int mt = 0; mt < 4; ++mt) {
      f32x4 a3[2] = {zero, zero};
      int am = mt * 16 + lr;
      for (int kc = 0; kc < 4; ++kc) {
        int kk = kc * 32 + q * 8;
        short8 af = *reinterpret_cast<const short8*>(&bufA[am * LD + kk]);
        for (int ot = 0; ot < 2; ++ot) a3[ot] = mfma16(af, w3f[kc][ot], a3[ot]);
      }
      for (int ot = 0; ot < 2; ++ot)
        for (int j = 0; j < 4; ++j) {
          int row = mt * 16 + q * 4 + j;
          bufB[row * LD + ow + ot * 16 + lr] = f2bf(fmaxf(a3[ot][j], 0.f));
        }
    }
  }
  __syncthreads();

  // ---- stage 6: out = relu([x | b2] @ Wf^T), K=256 split as WfL (x) + WfR (b2)
  {
    short8 wlf[4][2], wrf[4][2];
    for (int kc = 0; kc < 4; ++kc)
      for (int ot = 0; ot < 2; ++ot) {
        int o = ow + ot * 16 + lr;
        int kk = kc * 32 + q * 8;
        wlf[kc][ot] = ldwfrag(w_fusion + o * 256 + kk);
        wrf[kc][ot] = ldwfrag(w_fusion + o * 256 + 128 + kk);
      }
    f32x4 zero = {0.f, 0.f, 0.f, 0.f};
    for (int mt = 0; mt < 4; ++mt) {
      f32x4 a4[2] = {zero, zero};
      int am = mt * 16 + lr;
      for (int kc = 0; kc < 4; ++kc) {
        int kk = kc * 32 + q * 8;
        short8 afx = *reinterpret_cast<const short8*>(&xs[(am + 9) * LD + kk]);   // x at global n0+am
        a4[0] = mfma16(afx, wlf[kc][0], a4[0]);
        a4[1] = mfma16(afx, wlf[kc][1], a4[1]);
      }
      for (int kc = 0; kc < 4; ++kc) {
        int kk = kc * 32 + q * 8;
        short8 afb = *reinterpret_cast<const short8*>(&bufB[am * LD + kk]);       // b2
        a4[0] = mfma16(afb, wrf[kc][0], a4[0]);
        a4[1] = mfma16(afb, wrf[kc][1], a4[1]);
      }
      for (int ot = 0; ot < 2; ++ot)
        for (int j = 0; j < 4; ++j) {
          int grow = n0 + mt * 16 + q * 4 + j;
          out[grow * 128 + ow + ot * 16 + lr] = fmaxf(a4[ot][j], 0.f);
        }
    }
  }
}

extern "C" void kernel_launch(void* const* d_in, const int* in_sizes, int n_in,
                              void* d_out, int out_size, void* d_ws, size_t ws_size,
                              hipStream_t stream) {
  const float* x        = (const float*)d_in[0];
  const float* w_b1_dw  = (const float*)d_in[1];
  const float* w_b1_pw  = (const float*)d_in[2];
  const float* w_b2_1x1 = (const float*)d_in[3];
  const float* w_b2_dw  = (const float*)d_in[4];
  const float* w_b2_pw  = (const float*)d_in[5];
  const float* w_fusion = (const float*)d_in[6];
  (void)in_sizes; (void)n_in; (void)out_size; (void)d_ws; (void)ws_size;
  fused_block<<<dim3(N_DIM / BN), dim3(256), 0, stream>>>(
      x, w_b1_dw, w_b1_pw, w_b2_1x1, w_b2_dw, w_b2_pw, w_fusion, (float*)d_out);
}

// Round 2
// 250.943 us; speedup vs baseline: 1.0139x; 1.0139x over previous
//
#include <hip/hip_runtime.h>
#include <stdint.h>

#define N_DIM 131072
#define BN 62            // output rows per block
#define XR 66            // x rows [n0-2, n0+64)
#define MR 64            // d1/b2b rows [n0-1, n0+63); d2/b2 rows [n0, n0+64) (62 valid)
#define LD 136           // LDS row stride in ushorts: 128 + 8 pad (16B aligned)
#define NBLK ((N_DIM + BN - 1) / BN)

typedef __attribute__((ext_vector_type(8))) short short8;
typedef __attribute__((ext_vector_type(4))) float f32x4;

// pack two fp32 (as bits) -> two bf16 (truncation) in ONE v_perm_b32
__device__ __forceinline__ uint32_t pk2(uint32_t lo, uint32_t hi) {
  return __builtin_amdgcn_perm(hi, lo, 0x07060302u);
}
__device__ __forceinline__ uint32_t pkf(float lo, float hi) {
  union { float f; uint32_t u; } a, b; a.f = lo; b.f = hi;
  return __builtin_amdgcn_perm(b.u, a.u, 0x07060302u);
}
__device__ __forceinline__ float bflo(uint32_t u) { union { uint32_t u; float f; } v; v.u = u << 16;          return v.f; }
__device__ __forceinline__ float bfhi(uint32_t u) { union { uint32_t u; float f; } v; v.u = u & 0xFFFF0000u;  return v.f; }

__device__ __forceinline__ uint32_t rotl32(uint32_t x, int r) { return (x << r) | (x >> (32 - r)); }

// Threefry-2x32, 20 rounds, key = (0, 42)  [jax.random.key(42)] — verified R1
__device__ __forceinline__ void threefry42(uint32_t x0, uint32_t x1, uint32_t& o0, uint32_t& o1) {
  const uint32_t k0 = 0u, k1 = 42u, k2 = 0x1BD11BDAu ^ 0u ^ 42u;
  x0 += k0; x1 += k1;
#define TF_R(r) { x0 += x1; x1 = rotl32(x1, (r)); x1 ^= x0; }
  TF_R(13) TF_R(15) TF_R(26) TF_R(6)   x0 += k1; x1 += k2 + 1u;
  TF_R(17) TF_R(29) TF_R(16) TF_R(24)  x0 += k2; x1 += k0 + 2u;
  TF_R(13) TF_R(15) TF_R(26) TF_R(6)   x0 += k0; x1 += k1 + 3u;
  TF_R(17) TF_R(29) TF_R(16) TF_R(24)  x0 += k1; x1 += k2 + 4u;
  TF_R(13) TF_R(15) TF_R(26) TF_R(6)   x0 += k2; x1 += k0 + 5u;
#undef TF_R
  o0 = x0; o1 = x1;
}

// load 8 consecutive fp32, convert to bf16 A/B fragment (4 perms)
__device__ __forceinline__ short8 ldwfrag(const float* p) {
  uint4 a = reinterpret_cast<const uint4*>(p)[0];
  uint4 b = reinterpret_cast<const uint4*>(p)[1];
  union { uint32_t w[4]; short8 s; } r;
  r.w[0] = pk2(a.x, a.y); r.w[1] = pk2(a.z, a.w);
  r.w[2] = pk2(b.x, b.y); r.w[3] = pk2(b.z, b.w);
  return r.s;
}

__device__ __forceinline__ f32x4 mfma16(short8 a, short8 b, f32x4 c) {
  return __builtin_amdgcn_mfma_f32_16x16x32_bf16(a, b, c, 0, 0, 0);
}

// ---------- kernel 1: Bernoulli mask bits -> d_ws (1 bit per element) ----------
// word layout: mw[n*4 + (c>>5)] bit (c&31); keep iff MSB(y0^y1)==0, i = c*N + n
__global__ __launch_bounds__(256) void mask_gen(uint32_t* __restrict__ mw) {
  uint32_t gt = blockIdx.x * 256u + threadIdx.x;
  uint32_t n = gt >> 7, c = gt & 127u;
  uint32_t y0, y1;
  threefry42(0u, c * (uint32_t)N_DIM + n, y0, y1);
  unsigned long long ball = __ballot(((y0 ^ y1) >> 31) == 0u);
  uint32_t lane = threadIdx.x & 63u;
  if (lane == 0)       mw[n * 4u + (c >> 5)] = (uint32_t)ball;
  else if (lane == 32) mw[n * 4u + (c >> 5)] = (uint32_t)(ball >> 32);
}

// ---------- kernel 2: fused block ----------
__global__ __launch_bounds__(256, 3) void fused_block(
    const float* __restrict__ x,
    const float* __restrict__ w_b1_dw,
    const float* __restrict__ w_b1_pw,
    const float* __restrict__ w_b2_1x1,
    const float* __restrict__ w_b2_dw,
    const float* __restrict__ w_b2_pw,
    const float* __restrict__ w_fusion,
    const uint32_t* __restrict__ maskw,
    float* __restrict__ out)
{
  __shared__ ushort xs[XR * LD];      // x tile bf16, row r <-> global n0-2+r
  __shared__ ushort bufA[MR * LD];    // d1 (rows<->n0-1+r), later d2 (rows<->n0+r)
  __shared__ ushort bufB[MR * LD];    // b2b masked (n0-1+r), later b2 (n0+r)
  __shared__ uint32_t mlds[MR * 4];   // mask words for b2b rows

  const int tid  = threadIdx.x;
  const int n0   = blockIdx.x * BN;
  const int lane = tid & 63;
  const int wv   = tid >> 6;
  const int q    = lane >> 4;
  const int lr   = lane & 15;
  const int ow   = wv * 32;

  // ---- stage 1: x -> xs (bf16, trunc), mask words -> mlds
  {
    int r = tid >> 2, w = tid & 3, g = n0 - 1 + r;
    mlds[tid] = (g >= 0 && g < N_DIM) ? maskw[g * 4 + w] : 0u;
  }
  for (int u = tid; u < XR * 16; u += 256) {
    int r = u >> 4, grp = u & 15, g = n0 - 2 + r;
    uint4 a = {0u, 0u, 0u, 0u}, b = {0u, 0u, 0u, 0u};
    if (g >= 0 && g < N_DIM) {
      const uint4* p = reinterpret_cast<const uint4*>(x + g * 128 + grp * 8);
      a = p[0]; b = p[1];
    }
    uint4 st = { pk2(a.x, a.y), pk2(a.z, a.w), pk2(b.x, b.y), pk2(b.z, b.w) };
    *reinterpret_cast<uint4*>(&xs[r * LD + grp * 8]) = st;
  }
  __syncthreads();

  // ---- stage 2: dw1 (3-tap along N) -> bufA rows [0,64)
  {
    int c2 = (lane) * 2, rb = wv;
    float t0a = w_b1_dw[c2 * 9 + 1],  t1a = w_b1_dw[c2 * 9 + 4],  t2a = w_b1_dw[c2 * 9 + 7];
    float t0b = w_b1_dw[c2 * 9 + 10], t1b = w_b1_dw[c2 * 9 + 13], t2b = w_b1_dw[c2 * 9 + 16];
    #pragma unroll
    for (int k = 0; k < 16; ++k) {
      int r = rb + k * 4;                              // d1 row r <-> global n0-1+r, uses xs rows r..r+2
      uint32_t u0 = *reinterpret_cast<const uint32_t*>(&xs[r * LD + c2]);
      uint32_t u1 = *reinterpret_cast<const uint32_t*>(&xs[(r + 1) * LD + c2]);
      uint32_t u2 = *reinterpret_cast<const uint32_t*>(&xs[(r + 2) * LD + c2]);
      float lo = fmaxf(fmaf(t0a, bflo(u0), fmaf(t1a, bflo(u1), t2a * bflo(u2))), 0.f);
      float hi = fmaxf(fmaf(t0b, bfhi(u0), fmaf(t1b, bfhi(u1), t2b * bfhi(u2))), 0.f);
      *reinterpret_cast<uint32_t*>(&bufA[r * LD + c2]) = pkf(lo, hi);
    }
  }
  __syncthreads();

  // ---- stage 3: b2b = mask * (relu(d1@W1pw^T) + relu(x@W2a^T)) -> bufB, rows [0,64) exact
  {
    short8 w1f[4][2], w2f[4][2];
    #pragma unroll
    for (int kc = 0; kc < 4; ++kc)
      #pragma unroll
      for (int ot = 0; ot < 2; ++ot) {
        int o = ow + ot * 16 + lr, kk = kc * 32 + q * 8;
        w1f[kc][ot] = ldwfrag(w_b1_pw + o * 128 + kk);
        w2f[kc][ot] = ldwfrag(w_b2_1x1 + o * 128 + kk);
      }
    const f32x4 zero = {0.f, 0.f, 0.f, 0.f};
    #pragma unroll
    for (int mt = 0; mt < 4; ++mt) {
      f32x4 a1[2] = {zero, zero}, a2[2] = {zero, zero};
      int am = mt * 16 + lr;
      #pragma unroll
      for (int kc = 0; kc < 4; ++kc) {
        int kk = kc * 32 + q * 8;
        short8 af1 = *reinterpret_cast<const short8*>(&bufA[am * LD + kk]);       // d1
        short8 af2 = *reinterpret_cast<const short8*>(&xs[(am + 1) * LD + kk]);   // x same global row
        a1[0] = mfma16(af1, w1f[kc][0], a1[0]);
        a1[1] = mfma16(af1, w1f[kc][1], a1[1]);
        a2[0] = mfma16(af2, w2f[kc][0], a2[0]);
        a2[1] = mfma16(af2, w2f[kc][1], a2[1]);
      }
      #pragma unroll
      for (int ot = 0; ot < 2; ++ot)
        #pragma unroll
        for (int j = 0; j < 4; ++j) {
          int row = mt * 16 + q * 4 + j;               // D: col=lane&15, row=quad*4+reg
          float v = fmaxf(a1[ot][j], 0.f) + fmaxf(a2[ot][j], 0.f);
          uint32_t keep = (mlds[row * 4 + wv] >> (ot * 16 + lr)) & 1u;
          union { float f; uint32_t u; } cv; cv.f = v;
          bufB[row * LD + ow + ot * 16 + lr] = keep ? (ushort)(cv.u >> 16) : (ushort)0;
        }
    }
  }
  __syncthreads();

  // ---- stage 4: dw2 on b2b -> d2 (bufA), rows j in [0,62); uses b2b rows j..j+2
  {
    int c2 = (lane) * 2, rb = wv;
    float t0a = w_b2_dw[c2 * 9 + 1],  t1a = w_b2_dw[c2 * 9 + 4],  t2a = w_b2_dw[c2 * 9 + 7];
    float t0b = w_b2_dw[c2 * 9 + 10], t1b = w_b2_dw[c2 * 9 + 13], t2b = w_b2_dw[c2 * 9 + 16];
    #pragma unroll
    for (int k = 0; k < 16; ++k) {
      int j = rb + k * 4;
      if (j < BN) {
        uint32_t u0 = *reinterpret_cast<const uint32_t*>(&bufB[j * LD + c2]);
        uint32_t u1 = *reinterpret_cast<const uint32_t*>(&bufB[(j + 1) * LD + c2]);
        uint32_t u2 = *reinterpret_cast<const uint32_t*>(&bufB[(j + 2) * LD + c2]);
        float lo = fmaxf(fmaf(t0a, bflo(u0), fmaf(t1a, bflo(u1), t2a * bflo(u2))), 0.f);
        float hi = fmaxf(fmaf(t0b, bfhi(u0), fmaf(t1b, bfhi(u1), t2b * bfhi(u2))), 0.f);
        *reinterpret_cast<uint32_t*>(&bufA[j * LD + c2]) = pkf(lo, hi);
      }
    }
  }
  __syncthreads();

  // ---- stage 5: b2 = relu(d2 @ W2pw^T) -> bufB rows [0,62)
  {
    short8 w3f[4][2];
    #pragma unroll
    for (int kc = 0; kc < 4; ++kc)
      #pragma unroll
      for (int ot = 0; ot < 2; ++ot) {
        int o = ow + ot * 16 + lr, kk = kc * 32 + q * 8;
        w3f[kc][ot] = ldwfrag(w_b2_pw + o * 128 + kk);
      }
    const f32x4 zero = {0.f, 0.f, 0.f, 0.f};
    #pragma unroll
    for (int mt = 0; mt < 4; ++mt) {
      f32x4 a3[2] = {zero, zero};
      int am = mt * 16 + lr;                            // rows 62,63 read stale-but-finite data; discarded
      #pragma unroll
      for (int kc = 0; kc < 4; ++kc) {
        int kk = kc * 32 + q * 8;
        short8 af = *reinterpret_cast<const short8*>(&bufA[am * LD + kk]);
        a3[0] = mfma16(af, w3f[kc][0], a3[0]);
        a3[1] = mfma16(af, w3f[kc][1], a3[1]);
      }
      #pragma unroll
      for (int ot = 0; ot < 2; ++ot)
        #pragma unroll
        for (int j = 0; j < 4; ++j) {
          int row = mt * 16 + q * 4 + j;
          if (row < BN) {
            union { float f; uint32_t u; } cv; cv.f = fmaxf(a3[ot][j], 0.f);
            bufB[row * LD + ow + ot * 16 + lr] = (ushort)(cv.u >> 16);
          }
        }
    }
  }
  __syncthreads();

  // ---- stage 6: out = relu([x | b2] @ Wf^T), K=256
  {
    short8 wlf[4][2], wrf[4][2];
    #pragma unroll
    for (int kc = 0; kc < 4; ++kc)
      #pragma unroll
      for (int ot = 0; ot < 2; ++ot) {
        int o = ow + ot * 16 + lr, kk = kc * 32 + q * 8;
        wlf[kc][ot] = ldwfrag(w_fusion + o * 256 + kk);
        wrf[kc][ot] = ldwfrag(w_fusion + o * 256 + 128 + kk);
      }
    const f32x4 zero = {0.f, 0.f, 0.f, 0.f};
    #pragma unroll
    for (int mt = 0; mt < 4; ++mt) {
      f32x4 a4[2] = {zero, zero};
      int am = mt * 16 + lr;
      #pragma unroll
      for (int kc = 0; kc < 4; ++kc) {
        int kk = kc * 32 + q * 8;
        short8 afx = *reinterpret_cast<const short8*>(&xs[(am + 2) * LD + kk]);   // x at global n0+am
        a4[0] = mfma16(afx, wlf[kc][0], a4[0]);
        a4[1] = mfma16(afx, wlf[kc][1], a4[1]);
      }
      #pragma unroll
      for (int kc = 0; kc < 4; ++kc) {
        int kk = kc * 32 + q * 8;
        short8 afb = *reinterpret_cast<const short8*>(&bufB[am * LD + kk]);       // b2
        a4[0] = mfma16(afb, wrf[kc][0], a4[0]);
        a4[1] = mfma16(afb, wrf[kc][1], a4[1]);
      }
      #pragma unroll
      for (int ot = 0; ot < 2; ++ot)
        #pragma unroll
        for (int j = 0; j < 4; ++j) {
          int row = mt * 16 + q * 4 + j;
          int grow = n0 + row;
          if (row < BN && grow < N_DIM)
            out[grow * 128 + ow + ot * 16 + lr] = fmaxf(a4[ot][j], 0.f);
        }
    }
  }
}

extern "C" void kernel_launch(void* const* d_in, const int* in_sizes, int n_in,
                              void* d_out, int out_size, void* d_ws, size_t ws_size,
                              hipStream_t stream) {
  const float* x        = (const float*)d_in[0];
  const float* w_b1_dw  = (const float*)d_in[1];
  const float* w_b1_pw  = (const float*)d_in[2];
  const float* w_b2_1x1 = (const float*)d_in[3];
  const float* w_b2_dw  = (const float*)d_in[4];
  const float* w_b2_pw  = (const float*)d_in[5];
  const float* w_fusion = (const float*)d_in[6];
  uint32_t* maskw = (uint32_t*)d_ws;                 // N*4 words = 2 MB
  (void)in_sizes; (void)n_in; (void)out_size; (void)ws_size;
  mask_gen<<<dim3(N_DIM * 128 / 256), dim3(256), 0, stream>>>(maskw);
  fused_block<<<dim3(NBLK), dim3(256), 0, stream>>>(
      x, w_b1_dw, w_b1_pw, w_b2_1x1, w_b2_dw, w_b2_pw, w_fusion, maskw, (float*)d_out);
}

// Round 4
// 214.608 us; speedup vs baseline: 1.1856x; 1.1693x over previous
//
#include <hip/hip_runtime.h>
#include <stdint.h>

#define N_DIM 131072
#define BN 64            // rows per block (A and B), exact tiling
#define LD 136           // LDS row stride in ushorts: 128 + 8 pad (16B aligned)
#define NBLK (N_DIM / BN)

typedef __attribute__((ext_vector_type(8))) short short8;
typedef __attribute__((ext_vector_type(4))) float f32x4;

// pack two fp32 (as bits) -> two bf16 (truncation) in ONE v_perm_b32
__device__ __forceinline__ uint32_t pk2(uint32_t lo, uint32_t hi) {
  return __builtin_amdgcn_perm(hi, lo, 0x07060302u);
}
__device__ __forceinline__ uint32_t pkf(float lo, float hi) {
  union { float f; uint32_t u; } a, b; a.f = lo; b.f = hi;
  return __builtin_amdgcn_perm(b.u, a.u, 0x07060302u);
}
__device__ __forceinline__ float bflo(uint32_t u) { union { uint32_t u; float f; } v; v.u = u << 16;          return v.f; }
__device__ __forceinline__ float bfhi(uint32_t u) { union { uint32_t u; float f; } v; v.u = u & 0xFFFF0000u;  return v.f; }

__device__ __forceinline__ uint32_t rotl32(uint32_t x, int r) { return (x << r) | (x >> (32 - r)); }

// Threefry-2x32, 20 rounds, key = (0, 42) — verified R1/R2
__device__ __forceinline__ void threefry42(uint32_t x0, uint32_t x1, uint32_t& o0, uint32_t& o1) {
  const uint32_t k0 = 0u, k1 = 42u, k2 = 0x1BD11BDAu ^ 0u ^ 42u;
  x0 += k0; x1 += k1;
#define TF_R(r) { x0 += x1; x1 = rotl32(x1, (r)); x1 ^= x0; }
  TF_R(13) TF_R(15) TF_R(26) TF_R(6)   x0 += k1; x1 += k2 + 1u;
  TF_R(17) TF_R(29) TF_R(16) TF_R(24)  x0 += k2; x1 += k0 + 2u;
  TF_R(13) TF_R(15) TF_R(26) TF_R(6)   x0 += k0; x1 += k1 + 3u;
  TF_R(17) TF_R(29) TF_R(16) TF_R(24)  x0 += k1; x1 += k2 + 4u;
  TF_R(13) TF_R(15) TF_R(26) TF_R(6)   x0 += k2; x1 += k0 + 5u;
#undef TF_R
  o0 = x0; o1 = x1;
}

__device__ __forceinline__ short8 ldwfrag(const float* p) {
  uint4 a = reinterpret_cast<const uint4*>(p)[0];
  uint4 b = reinterpret_cast<const uint4*>(p)[1];
  union { uint32_t w[4]; short8 s; } r;
  r.w[0] = pk2(a.x, a.y); r.w[1] = pk2(a.z, a.w);
  r.w[2] = pk2(b.x, b.y); r.w[3] = pk2(b.z, b.w);
  return r.s;
}

__device__ __forceinline__ f32x4 mfma16(short8 a, short8 b, f32x4 c) {
  return __builtin_amdgcn_mfma_f32_16x16x32_bf16(a, b, c, 0, 0, 0);
}

// ================= kernel A: x -> b2b (masked), b2b to global ws =================
// block: 64 rows [m0, m0+64). xs rows [m0-1, m0+65). 2 barriers, ~36 KB LDS.
__global__ __launch_bounds__(256, 4) void fusedA(
    const float* __restrict__ x,
    const float* __restrict__ w_b1_dw,
    const float* __restrict__ w_b1_pw,
    const float* __restrict__ w_b2_1x1,
    ushort* __restrict__ b2bg)
{
  __shared__ ushort xs[66 * LD];     // row r <-> global m0-1+r
  __shared__ ushort d1[64 * LD];     // row r <-> global m0+r
  __shared__ uint32_t mlds[256];     // mask words, 64 rows x 4

  const int tid  = threadIdx.x;
  const int m0   = blockIdx.x * BN;
  const int lane = tid & 63;
  const int wv   = tid >> 6;
  const int q    = lane >> 4;
  const int lr   = lane & 15;
  const int ow   = wv * 32;

  // stage 1: x -> xs (bf16 trunc)
  for (int u = tid; u < 66 * 16; u += 256) {
    int r = u >> 4, grp = u & 15, g = m0 - 1 + r;
    uint4 a = {0u, 0u, 0u, 0u}, b = {0u, 0u, 0u, 0u};
    if (g >= 0 && g < N_DIM) {
      const uint4* p = reinterpret_cast<const uint4*>(x + (size_t)g * 128 + grp * 8);
      a = p[0]; b = p[1];
    }
    uint4 st = { pk2(a.x, a.y), pk2(a.z, a.w), pk2(b.x, b.y), pk2(b.z, b.w) };
    *reinterpret_cast<uint4*>(&xs[r * LD + grp * 8]) = st;
  }

  // stage 1b: threefry mask, 1 word/thread (overlaps staging latency)
  {
    uint32_t row = (uint32_t)(tid >> 2), wi = (uint32_t)(tid & 3);
    uint32_t n = (uint32_t)m0 + row;
    uint32_t bits = 0;
    #pragma unroll 4
    for (uint32_t j = 0; j < 32; ++j) {
      uint32_t y0, y1;
      threefry42(0u, (wi * 32u + j) * (uint32_t)N_DIM + n, y0, y1);
      bits |= ((((y0 ^ y1) >> 31) ^ 1u)) << j;     // bit=1 => keep
    }
    mlds[tid] = bits;
  }

  // prefetch stage-3 weight fragments
  short8 w1f[4][2], w2f[4][2];
  #pragma unroll
  for (int kc = 0; kc < 4; ++kc) {
    #pragma unroll
    for (int ot = 0; ot < 2; ++ot) {
      int o = ow + ot * 16 + lr, kk = kc * 32 + q * 8;
      w1f[kc][ot] = ldwfrag(w_b1_pw + o * 128 + kk);
      w2f[kc][ot] = ldwfrag(w_b2_1x1 + o * 128 + kk);
    }
  }
  __syncthreads();

  // stage 2: dw1 (3-tap along N) -> d1 rows [0,64)
  {
    int c2 = lane * 2;
    float t0a = w_b1_dw[c2 * 9 + 1],  t1a = w_b1_dw[c2 * 9 + 4],  t2a = w_b1_dw[c2 * 9 + 7];
    float t0b = w_b1_dw[c2 * 9 + 10], t1b = w_b1_dw[c2 * 9 + 13], t2b = w_b1_dw[c2 * 9 + 16];
    #pragma unroll
    for (int k = 0; k < 16; ++k) {
      int r = wv + k * 4;                            // d1 row r (global m0+r), uses xs r..r+2
      uint32_t u0 = *reinterpret_cast<const uint32_t*>(&xs[r * LD + c2]);
      uint32_t u1 = *reinterpret_cast<const uint32_t*>(&xs[(r + 1) * LD + c2]);
      uint32_t u2 = *reinterpret_cast<const uint32_t*>(&xs[(r + 2) * LD + c2]);
      float lo = fmaxf(fmaf(t0a, bflo(u0), fmaf(t1a, bflo(u1), t2a * bflo(u2))), 0.f);
      float hi = fmaxf(fmaf(t0b, bfhi(u0), fmaf(t1b, bfhi(u1), t2b * bfhi(u2))), 0.f);
      *reinterpret_cast<uint32_t*>(&d1[r * LD + c2]) = pkf(lo, hi);
    }
  }
  __syncthreads();

  // stage 3: b2b = mask * (relu(d1@W1pw^T) + relu(x@W2a^T)) -> global
  {
    const f32x4 zero = {0.f, 0.f, 0.f, 0.f};
    #pragma unroll
    for (int mt = 0; mt < 4; ++mt) {
      f32x4 a1[2] = {zero, zero}, a2[2] = {zero, zero};
      int am = mt * 16 + lr;
      #pragma unroll
      for (int kc = 0; kc < 4; ++kc) {
        int kk = kc * 32 + q * 8;
        short8 af1 = *reinterpret_cast<const short8*>(&d1[am * LD + kk]);
        short8 af2 = *reinterpret_cast<const short8*>(&xs[(am + 1) * LD + kk]);
        a1[0] = mfma16(af1, w1f[kc][0], a1[0]);
        a1[1] = mfma16(af1, w1f[kc][1], a1[1]);
        a2[0] = mfma16(af2, w2f[kc][0], a2[0]);
        a2[1] = mfma16(af2, w2f[kc][1], a2[1]);
      }
      #pragma unroll
      for (int ot = 0; ot < 2; ++ot) {
        #pragma unroll
        for (int j = 0; j < 4; ++j) {
          int row = mt * 16 + q * 4 + j;             // D: col=lane&15, row=quad*4+reg
          float v = fmaxf(a1[ot][j], 0.f) + fmaxf(a2[ot][j], 0.f);
          uint32_t keep = (mlds[row * 4 + wv] >> (ot * 16 + lr)) & 1u;
          union { float f; uint32_t u; } cv; cv.f = v;
          b2bg[(size_t)(m0 + row) * 128 + ow + ot * 16 + lr] = keep ? (ushort)(cv.u >> 16) : (ushort)0;
        }
      }
    }
  }
}

// ================= kernel B: b2b -> out =================
__global__ __launch_bounds__(256, 3) void fusedB(
    const ushort* __restrict__ b2bg,
    const float* __restrict__ x,
    const float* __restrict__ w_b2_dw,
    const float* __restrict__ w_b2_pw,
    const float* __restrict__ w_fusion,
    float* __restrict__ out)
{
  __shared__ ushort bbs[66 * LD];    // b2b tile (r <-> m0-1+r); later b2 (r <-> m0+r)
  __shared__ ushort d2s[64 * LD];    // d2 (r <-> m0+r)
  __shared__ ushort xs2[64 * LD];    // x tile bf16 (r <-> m0+r)

  const int tid  = threadIdx.x;
  const int m0   = blockIdx.x * BN;
  const int lane = tid & 63;
  const int wv   = tid >> 6;
  const int q    = lane >> 4;
  const int lr   = lane & 15;
  const int ow   = wv * 32;

  // stage 1: b2b -> bbs (zero-pad OOB rows)
  for (int u = tid; u < 66 * 16; u += 256) {
    int r = u >> 4, grp = u & 15, g = m0 - 1 + r;
    uint4 st = {0u, 0u, 0u, 0u};
    if (g >= 0 && g < N_DIM)
      st = reinterpret_cast<const uint4*>(b2bg + (size_t)g * 128)[grp];
    *reinterpret_cast<uint4*>(&bbs[r * LD + grp * 8]) = st;
  }
  // stage 1b: x -> xs2 (bf16 trunc), rows [m0, m0+64)
  for (int u = tid; u < 64 * 16; u += 256) {
    int r = u >> 4, grp = u & 15, g = m0 + r;
    const uint4* p = reinterpret_cast<const uint4*>(x + (size_t)g * 128 + grp * 8);
    uint4 a = p[0], b = p[1];
    uint4 st = { pk2(a.x, a.y), pk2(a.z, a.w), pk2(b.x, b.y), pk2(b.z, b.w) };
    *reinterpret_cast<uint4*>(&xs2[r * LD + grp * 8]) = st;
  }
  // prefetch GEMM3 weights
  short8 w3f[4][2];
  #pragma unroll
  for (int kc = 0; kc < 4; ++kc) {
    #pragma unroll
    for (int ot = 0; ot < 2; ++ot) {
      int o = ow + ot * 16 + lr, kk = kc * 32 + q * 8;
      w3f[kc][ot] = ldwfrag(w_b2_pw + o * 128 + kk);
    }
  }
  __syncthreads();

  // stage 2: dw2 -> d2s rows [0,64): row j uses bbs j..j+2
  {
    int c2 = lane * 2;
    float t0a = w_b2_dw[c2 * 9 + 1],  t1a = w_b2_dw[c2 * 9 + 4],  t2a = w_b2_dw[c2 * 9 + 7];
    float t0b = w_b2_dw[c2 * 9 + 10], t1b = w_b2_dw[c2 * 9 + 13], t2b = w_b2_dw[c2 * 9 + 16];
    #pragma unroll
    for (int k = 0; k < 16; ++k) {
      int j = wv + k * 4;
      uint32_t u0 = *reinterpret_cast<const uint32_t*>(&bbs[j * LD + c2]);
      uint32_t u1 = *reinterpret_cast<const uint32_t*>(&bbs[(j + 1) * LD + c2]);
      uint32_t u2 = *reinterpret_cast<const uint32_t*>(&bbs[(j + 2) * LD + c2]);
      float lo = fmaxf(fmaf(t0a, bflo(u0), fmaf(t1a, bflo(u1), t2a * bflo(u2))), 0.f);
      float hi = fmaxf(fmaf(t0b, bfhi(u0), fmaf(t1b, bfhi(u1), t2b * bfhi(u2))), 0.f);
      *reinterpret_cast<uint32_t*>(&d2s[j * LD + c2]) = pkf(lo, hi);
    }
  }
  // prefetch fusion left-half (x side) weights
  short8 wlf[4][2];
  #pragma unroll
  for (int kc = 0; kc < 4; ++kc) {
    #pragma unroll
    for (int ot = 0; ot < 2; ++ot) {
      int o = ow + ot * 16 + lr, kk = kc * 32 + q * 8;
      wlf[kc][ot] = ldwfrag(w_fusion + o * 256 + kk);
    }
  }
  __syncthreads();

  // stage 3: b2 = relu(d2 @ W2pw^T) -> bbs rows [0,64)  (bbs free after dw2+barrier)
  {
    const f32x4 zero = {0.f, 0.f, 0.f, 0.f};
    #pragma unroll
    for (int mt = 0; mt < 4; ++mt) {
      f32x4 a3[2] = {zero, zero};
      int am = mt * 16 + lr;
      #pragma unroll
      for (int kc = 0; kc < 4; ++kc) {
        int kk = kc * 32 + q * 8;
        short8 af = *reinterpret_cast<const short8*>(&d2s[am * LD + kk]);
        a3[0] = mfma16(af, w3f[kc][0], a3[0]);
        a3[1] = mfma16(af, w3f[kc][1], a3[1]);
      }
      #pragma unroll
      for (int ot = 0; ot < 2; ++ot) {
        #pragma unroll
        for (int j = 0; j < 4; ++j) {
          int row = mt * 16 + q * 4 + j;
          union { float f; uint32_t u; } cv; cv.f = fmaxf(a3[ot][j], 0.f);
          bbs[row * LD + ow + ot * 16 + lr] = (ushort)(cv.u >> 16);
        }
      }
    }
  }

  // prefetch fusion right-half weights; GEMM4a (x-half) fills the barrier drain
  short8 wrf[4][2];
  #pragma unroll
  for (int kc = 0; kc < 4; ++kc) {
    #pragma unroll
    for (int ot = 0; ot < 2; ++ot) {
      int o = ow + ot * 16 + lr, kk = kc * 32 + q * 8;
      wrf[kc][ot] = ldwfrag(w_fusion + o * 256 + 128 + kk);
    }
  }
  f32x4 a4[4][2];
  #pragma unroll
  for (int mt = 0; mt < 4; ++mt) {
    a4[mt][0] = (f32x4){0.f, 0.f, 0.f, 0.f};
    a4[mt][1] = (f32x4){0.f, 0.f, 0.f, 0.f};
    int am = mt * 16 + lr;
    #pragma unroll
    for (int kc = 0; kc < 4; ++kc) {
      int kk = kc * 32 + q * 8;
      short8 afx = *reinterpret_cast<const short8*>(&xs2[am * LD + kk]);
      a4[mt][0] = mfma16(afx, wlf[kc][0], a4[mt][0]);
      a4[mt][1] = mfma16(afx, wlf[kc][1], a4[mt][1]);
    }
  }
  __syncthreads();

  // stage 4: += b2 @ WfR^T ; write out
  #pragma unroll
  for (int mt = 0; mt < 4; ++mt) {
    int am = mt * 16 + lr;
    #pragma unroll
    for (int kc = 0; kc < 4; ++kc) {
      int kk = kc * 32 + q * 8;
      short8 afb = *reinterpret_cast<const short8*>(&bbs[am * LD + kk]);
      a4[mt][0] = mfma16(afb, wrf[kc][0], a4[mt][0]);
      a4[mt][1] = mfma16(afb, wrf[kc][1], a4[mt][1]);
    }
    #pragma unroll
    for (int ot = 0; ot < 2; ++ot) {
      #pragma unroll
      for (int j = 0; j < 4; ++j) {
        int row = mt * 16 + q * 4 + j;
        out[(size_t)(m0 + row) * 128 + ow + ot * 16 + lr] = fmaxf(a4[mt][ot][j], 0.f);
      }
    }
  }
}

// ================= fallback path (R2-proven structure) — used only if ws too small
#define BN_M 62
#define NBLK_M ((N_DIM + BN_M - 1) / BN_M)

__global__ __launch_bounds__(256) void mask_gen_fb(uint32_t* __restrict__ mw) {
  uint32_t gt = blockIdx.x * 256u + threadIdx.x;
  uint32_t n = gt >> 7, c = gt & 127u;
  uint32_t y0, y1;
  threefry42(0u, c * (uint32_t)N_DIM + n, y0, y1);
  unsigned long long ball = __ballot(((y0 ^ y1) >> 31) == 0u);
  uint32_t lane = threadIdx.x & 63u;
  if (lane == 0)       mw[n * 4u + (c >> 5)] = (uint32_t)ball;
  else if (lane == 32) mw[n * 4u + (c >> 5)] = (uint32_t)(ball >> 32);
}

__global__ __launch_bounds__(256, 3) void fused_mono(
    const float* __restrict__ x, const float* __restrict__ w_b1_dw,
    const float* __restrict__ w_b1_pw, const float* __restrict__ w_b2_1x1,
    const float* __restrict__ w_b2_dw, const float* __restrict__ w_b2_pw,
    const float* __restrict__ w_fusion, const uint32_t* __restrict__ maskw,
    float* __restrict__ out)
{
  __shared__ ushort xs[66 * LD];
  __shared__ ushort bufA[64 * LD];
  __shared__ ushort bufB[64 * LD];
  __shared__ uint32_t mlds[64 * 4];

  const int tid = threadIdx.x, n0 = blockIdx.x * BN_M;
  const int lane = tid & 63, wv = tid >> 6, q = lane >> 4, lr = lane & 15, ow = wv * 32;

  {
    int r = tid >> 2, w = tid & 3, g = n0 - 1 + r;
    mlds[tid] = (g >= 0 && g < N_DIM) ? maskw[g * 4 + w] : 0u;
  }
  for (int u = tid; u < 66 * 16; u += 256) {
    int r = u >> 4, grp = u & 15, g = n0 - 2 + r;
    uint4 a = {0u, 0u, 0u, 0u}, b = {0u, 0u, 0u, 0u};
    if (g >= 0 && g < N_DIM) {
      const uint4* p = reinterpret_cast<const uint4*>(x + (size_t)g * 128 + grp * 8);
      a = p[0]; b = p[1];
    }
    uint4 st = { pk2(a.x, a.y), pk2(a.z, a.w), pk2(b.x, b.y), pk2(b.z, b.w) };
    *reinterpret_cast<uint4*>(&xs[r * LD + grp * 8]) = st;
  }
  __syncthreads();

  {
    int c2 = lane * 2;
    float t0a = w_b1_dw[c2 * 9 + 1],  t1a = w_b1_dw[c2 * 9 + 4],  t2a = w_b1_dw[c2 * 9 + 7];
    float t0b = w_b1_dw[c2 * 9 + 10], t1b = w_b1_dw[c2 * 9 + 13], t2b = w_b1_dw[c2 * 9 + 16];
    #pragma unroll
    for (int k = 0; k < 16; ++k) {
      int r = wv + k * 4;
      uint32_t u0 = *reinterpret_cast<const uint32_t*>(&xs[r * LD + c2]);
      uint32_t u1 = *reinterpret_cast<const uint32_t*>(&xs[(r + 1) * LD + c2]);
      uint32_t u2 = *reinterpret_cast<const uint32_t*>(&xs[(r + 2) * LD + c2]);
      float lo = fmaxf(fmaf(t0a, bflo(u0), fmaf(t1a, bflo(u1), t2a * bflo(u2))), 0.f);
      float hi = fmaxf(fmaf(t0b, bfhi(u0), fmaf(t1b, bfhi(u1), t2b * bfhi(u2))), 0.f);
      *reinterpret_cast<uint32_t*>(&bufA[r * LD + c2]) = pkf(lo, hi);
    }
  }
  __syncthreads();

  {
    short8 w1f[4][2], w2f[4][2];
    #pragma unroll
    for (int kc = 0; kc < 4; ++kc) {
      #pragma unroll
      for (int ot = 0; ot < 2; ++ot) {
        int o = ow + ot * 16 + lr, kk = kc * 32 + q * 8;
        w1f[kc][ot] = ldwfrag(w_b1_pw + o * 128 + kk);
        w2f[kc][ot] = ldwfrag(w_b2_1x1 + o * 128 + kk);
      }
    }
    const f32x4 zero = {0.f, 0.f, 0.f, 0.f};
    #pragma unroll
    for (int mt = 0; mt < 4; ++mt) {
      f32x4 a1[2] = {zero, zero}, a2[2] = {zero, zero};
      int am = mt * 16 + lr;
      #pragma unroll
      for (int kc = 0; kc < 4; ++kc) {
        int kk = kc * 32 + q * 8;
        short8 af1 = *reinterpret_cast<const short8*>(&bufA[am * LD + kk]);
        short8 af2 = *reinterpret_cast<const short8*>(&xs[(am + 1) * LD + kk]);
        a1[0] = mfma16(af1, w1f[kc][0], a1[0]);
        a1[1] = mfma16(af1, w1f[kc][1], a1[1]);
        a2[0] = mfma16(af2, w2f[kc][0], a2[0]);
        a2[1] = mfma16(af2, w2f[kc][1], a2[1]);
      }
      #pragma unroll
      for (int ot = 0; ot < 2; ++ot) {
        #pragma unroll
        for (int j = 0; j < 4; ++j) {
          int row = mt * 16 + q * 4 + j;
          float v = fmaxf(a1[ot][j], 0.f) + fmaxf(a2[ot][j], 0.f);
          uint32_t keep = (mlds[row * 4 + wv] >> (ot * 16 + lr)) & 1u;
          union { float f; uint32_t u; } cv; cv.f = v;
          bufB[row * LD + ow + ot * 16 + lr] = keep ? (ushort)(cv.u >> 16) : (ushort)0;
        }
      }
    }
  }
  __syncthreads();

  {
    int c2 = lane * 2;
    float t0a = w_b2_dw[c2 * 9 + 1],  t1a = w_b2_dw[c2 * 9 + 4],  t2a = w_b2_dw[c2 * 9 + 7];
    float t0b = w_b2_dw[c2 * 9 + 10], t1b = w_b2_dw[c2 * 9 + 13], t2b = w_b2_dw[c2 * 9 + 16];
    #pragma unroll
    for (int k = 0; k < 16; ++k) {
      int j = wv + k * 4;
      if (j < BN_M) {
        uint32_t u0 = *reinterpret_cast<const uint32_t*>(&bufB[j * LD + c2]);
        uint32_t u1 = *reinterpret_cast<const uint32_t*>(&bufB[(j + 1) * LD + c2]);
        uint32_t u2 = *reinterpret_cast<const uint32_t*>(&bufB[(j + 2) * LD + c2]);
        float lo = fmaxf(fmaf(t0a, bflo(u0), fmaf(t1a, bflo(u1), t2a * bflo(u2))), 0.f);
        float hi = fmaxf(fmaf(t0b, bfhi(u0), fmaf(t1b, bfhi(u1), t2b * bfhi(u2))), 0.f);
        *reinterpret_cast<uint32_t*>(&bufA[j * LD + c2]) = pkf(lo, hi);
      }
    }
  }
  __syncthreads();

  {
    short8 w3f[4][2];
    #pragma unroll
    for (int kc = 0; kc < 4; ++kc) {
      #pragma unroll
      for (int ot = 0; ot < 2; ++ot) {
        int o = ow + ot * 16 + lr, kk = kc * 32 + q * 8;
        w3f[kc][ot] = ldwfrag(w_b2_pw + o * 128 + kk);
      }
    }
    const f32x4 zero = {0.f, 0.f, 0.f, 0.f};
    #pragma unroll
    for (int mt = 0; mt < 4; ++mt) {
      f32x4 a3[2] = {zero, zero};
      int am = mt * 16 + lr;
      #pragma unroll
      for (int kc = 0; kc < 4; ++kc) {
        int kk = kc * 32 + q * 8;
        short8 af = *reinterpret_cast<const short8*>(&bufA[am * LD + kk]);
        a3[0] = mfma16(af, w3f[kc][0], a3[0]);
        a3[1] = mfma16(af, w3f[kc][1], a3[1]);
      }
      #pragma unroll
      for (int ot = 0; ot < 2; ++ot) {
        #pragma unroll
        for (int j = 0; j < 4; ++j) {
          int row = mt * 16 + q * 4 + j;
          if (row < BN_M) {
            union { float f; uint32_t u; } cv; cv.f = fmaxf(a3[ot][j], 0.f);
            bufB[row * LD + ow + ot * 16 + lr] = (ushort)(cv.u >> 16);
          }
        }
      }
    }
  }
  __syncthreads();

  {
    short8 wlf[4][2], wrf[4][2];
    #pragma unroll
    for (int kc = 0; kc < 4; ++kc) {
      #pragma unroll
      for (int ot = 0; ot < 2; ++ot) {
        int o = ow + ot * 16 + lr, kk = kc * 32 + q * 8;
        wlf[kc][ot] = ldwfrag(w_fusion + o * 256 + kk);
        wrf[kc][ot] = ldwfrag(w_fusion + o * 256 + 128 + kk);
      }
    }
    const f32x4 zero = {0.f, 0.f, 0.f, 0.f};
    #pragma unroll
    for (int mt = 0; mt < 4; ++mt) {
      f32x4 a4[2] = {zero, zero};
      int am = mt * 16 + lr;
      #pragma unroll
      for (int kc = 0; kc < 4; ++kc) {
        int kk = kc * 32 + q * 8;
        short8 afx = *reinterpret_cast<const short8*>(&xs[(am + 2) * LD + kk]);
        a4[0] = mfma16(afx, wlf[kc][0], a4[0]);
        a4[1] = mfma16(afx, wlf[kc][1], a4[1]);
      }
      #pragma unroll
      for (int kc = 0; kc < 4; ++kc) {
        int kk = kc * 32 + q * 8;
        short8 afb = *reinterpret_cast<const short8*>(&bufB[am * LD + kk]);
        a4[0] = mfma16(afb, wrf[kc][0], a4[0]);
        a4[1] = mfma16(afb, wrf[kc][1], a4[1]);
      }
      #pragma unroll
      for (int ot = 0; ot < 2; ++ot) {
        #pragma unroll
        for (int j = 0; j < 4; ++j) {
          int row = mt * 16 + q * 4 + j;
          int grow = n0 + row;
          if (row < BN_M && grow < N_DIM)
            out[(size_t)grow * 128 + ow + ot * 16 + lr] = fmaxf(a4[ot][j], 0.f);
        }
      }
    }
  }
}

extern "C" void kernel_launch(void* const* d_in, const int* in_sizes, int n_in,
                              void* d_out, int out_size, void* d_ws, size_t ws_size,
                              hipStream_t stream) {
  const float* x        = (const float*)d_in[0];
  const float* w_b1_dw  = (const float*)d_in[1];
  const float* w_b1_pw  = (const float*)d_in[2];
  const float* w_b2_1x1 = (const float*)d_in[3];
  const float* w_b2_dw  = (const float*)d_in[4];
  const float* w_b2_pw  = (const float*)d_in[5];
  const float* w_fusion = (const float*)d_in[6];
  (void)in_sizes; (void)n_in; (void)out_size;

  const size_t need = (size_t)N_DIM * 128 * sizeof(ushort);   // 33.5 MB for b2b
  if (ws_size >= need) {
    ushort* b2bg = (ushort*)d_ws;
    fusedA<<<dim3(NBLK), dim3(256), 0, stream>>>(x, w_b1_dw, w_b1_pw, w_b2_1x1, b2bg);
    fusedB<<<dim3(NBLK), dim3(256), 0, stream>>>(b2bg, x, w_b2_dw, w_b2_pw, w_fusion, (float*)d_out);
  } else {
    uint32_t* maskw = (uint32_t*)d_ws;                        // 2 MB (R2-proven)
    mask_gen_fb<<<dim3(N_DIM * 128 / 256), dim3(256), 0, stream>>>(maskw);
    fused_mono<<<dim3(NBLK_M), dim3(256), 0, stream>>>(
        x, w_b1_dw, w_b1_pw, w_b2_1x1, w_b2_dw, w_b2_pw, w_fusion, maskw, (float*)d_out);
  }
}